// Round 1
// baseline (680.643 us; speedup 1.0000x reference)
//
#include <hip/hip_runtime.h>

// GraphSAGE 3-layer + head, fp32, MI355X.
// Structure:
//   CSR build (count/scan/fill) once per call
//   L1: agg(x, D=64) -> m; h1 = relu([m|x] @ [Wf_l;Wf_r] + bf)        (dual-A GEMM, K=128, Dout=256)
//   L2: C2 = h1 @ [W0_l|W0_r] (K=256, Dout=256); h2 = relu(mean(y2)+z2+b0)
//   L3: C3 = h2 @ [W1_l|W1_r] (K=128, Dout=256); h3 = relu(mean(y3)+z3+b1)
//   head: out = h3 @ (W_lin@W_lin2) + (b_lin@W_lin2 + b_lin2)

// ---------------- CSR build ----------------
__global__ __launch_bounds__(256) void count_k(const int* __restrict__ tgt, int* __restrict__ cnt, int E) {
  int e = blockIdx.x * 256 + threadIdx.x;
  if (e < E) atomicAdd(&cnt[tgt[e]], 1);
}

__global__ __launch_bounds__(1024) void scan_block_k(const int* __restrict__ cnt, int* __restrict__ row_ptr,
                                                     int* __restrict__ bsum, int N) {
  __shared__ int sh[1024];
  int tid = threadIdx.x;
  int i = blockIdx.x * 1024 + tid;
  int v = (i < N) ? cnt[i] : 0;
  int val = v;
  sh[tid] = val;
  __syncthreads();
  for (int off = 1; off < 1024; off <<= 1) {
    int t = (tid >= off) ? sh[tid - off] : 0;
    __syncthreads();
    val += t;
    sh[tid] = val;
    __syncthreads();
  }
  if (i < N) row_ptr[i] = val - v;      // exclusive
  if (tid == 1023) bsum[blockIdx.x] = val;
}

__global__ void scan_bsum_k(const int* __restrict__ bsum, int* __restrict__ boff,
                            int* __restrict__ row_ptr, int nb, int N) {
  if (threadIdx.x == 0 && blockIdx.x == 0) {
    int run = 0;
    for (int b = 0; b < nb; ++b) { boff[b] = run; run += bsum[b]; }
    row_ptr[N] = run;
  }
}

__global__ __launch_bounds__(1024) void scan_add_k(int* __restrict__ row_ptr, int* __restrict__ cursor,
                                                   const int* __restrict__ boff, int N) {
  int i = blockIdx.x * 1024 + threadIdx.x;
  if (i < N) {
    int v = row_ptr[i] + boff[blockIdx.x];
    row_ptr[i] = v;
    cursor[i] = v;
  }
}

__global__ __launch_bounds__(256) void fill_k(const int* __restrict__ src, const int* __restrict__ tgt,
                                              int* __restrict__ cursor, int* __restrict__ srcs, int E) {
  int e = blockIdx.x * 256 + threadIdx.x;
  if (e < E) {
    int pos = atomicAdd(&cursor[tgt[e]], 1);
    srcs[pos] = src[e];
  }
}

// ---------------- weight packing ----------------
// row-concat: dst[0:kl*cols] = Wl, dst[kl*cols:] = Wr   (both row-major, same #cols)
__global__ __launch_bounds__(256) void pack_rows_k(const float* __restrict__ Wl, const float* __restrict__ Wr,
                                                   float* __restrict__ dst, int half) {
  int t = blockIdx.x * 256 + threadIdx.x;
  if (t < 2 * half) dst[t] = (t < half) ? Wl[t] : Wr[t - half];
}

// col-concat: dst[k][0:H] = Wl[k], dst[k][H:2H] = Wr[k]   (Wl,Wr: K x H row-major)
__global__ __launch_bounds__(256) void pack_cols_k(const float* __restrict__ Wl, const float* __restrict__ Wr,
                                                   float* __restrict__ dst, int K, int H) {
  int t = blockIdx.x * 256 + threadIdx.x;
  if (t >= K * 2 * H) return;
  int k = t / (2 * H);
  int c = t - k * 2 * H;
  dst[t] = (c < H) ? Wl[k * H + c] : Wr[k * H + (c - H)];
}

// Wc[128x8] = W_lin(128x128) @ W_lin2(128x8); bc[8] = b_lin @ W_lin2 + b_lin2
__global__ __launch_bounds__(256) void comb_k(const float* __restrict__ Wlin, const float* __restrict__ blin,
                                              const float* __restrict__ Wlin2, const float* __restrict__ blin2,
                                              float* __restrict__ Wc, float* __restrict__ bc) {
  int t = blockIdx.x * 256 + threadIdx.x;
  if (t < 1024) {
    int i = t >> 3, j = t & 7;
    float acc = 0.f;
    for (int k = 0; k < 128; ++k) acc = fmaf(Wlin[i * 128 + k], Wlin2[k * 8 + j], acc);
    Wc[t] = acc;
  }
  if (t < 8) {
    float acc = blin2[t];
    for (int k = 0; k < 128; ++k) acc = fmaf(blin[k], Wlin2[k * 8 + t], acc);
    bc[t] = acc;
  }
}

// ---------------- aggregation ----------------
// wave per node, D=64, one float per lane: m[i] = mean_{j in N(i)} x[j]
__global__ __launch_bounds__(256) void agg_mean64_k(const float* __restrict__ x, const int* __restrict__ rp,
                                                    const int* __restrict__ srcs, float* __restrict__ m, int n) {
  int w = threadIdx.x >> 6, lane = threadIdx.x & 63;
  int node = blockIdx.x * 4 + w;
  if (node >= n) return;
  int s0 = rp[node], s1 = rp[node + 1];
  float sum = 0.f;
  for (int e = s0; e < s1; ++e) {
    int s = srcs[e];
    sum += x[(size_t)s * 64 + lane];
  }
  int deg = s1 - s0;
  float inv = 1.f / (float)(deg > 0 ? deg : 1);
  m[(size_t)node * 64 + lane] = sum * inv;
}

// wave per node, D=128 (float2/lane). C is N x 256: cols 0..127 = y (aggregate), 128..255 = z.
// hout[i] = relu(mean_j y[j] + z[i] + bias)
__global__ __launch_bounds__(256) void agg_mean128_k(const float* __restrict__ C, const float* __restrict__ bias,
                                                     const int* __restrict__ rp, const int* __restrict__ srcs,
                                                     float* __restrict__ hout, int n) {
  int w = threadIdx.x >> 6, lane = threadIdx.x & 63;
  int node = blockIdx.x * 4 + w;
  if (node >= n) return;
  int s0 = rp[node], s1 = rp[node + 1];
  int d = lane * 2;
  float sx = 0.f, sy = 0.f;
  for (int e = s0; e < s1; ++e) {
    int s = srcs[e];
    const float2 v = *(const float2*)&C[(size_t)s * 256 + d];
    sx += v.x; sy += v.y;
  }
  int deg = s1 - s0;
  float inv = 1.f / (float)(deg > 0 ? deg : 1);
  float2 z = *(const float2*)&C[(size_t)node * 256 + 128 + d];
  float2 b = *(const float2*)&bias[d];
  float ox = fmaxf(fmaf(sx, inv, z.x + b.x), 0.f);
  float oy = fmaxf(fmaf(sy, inv, z.y + b.y), 0.f);
  *(float2*)&hout[(size_t)node * 128 + d] = make_float2(ox, oy);
}

// ---------------- GEMM: C[N x ldc tile] = [A1|A2] @ W (+bias)(relu) ----------------
// BM=64 BN=64 BK=32, 256 threads, 4x4 per thread.
// A1: N x K1, A2: N x (Ktot-K1), both row-major. W: Ktot x ldc row-major (packed).
template <int RELU, int HASBIAS>
__global__ __launch_bounds__(256) void gemm_k(const float* __restrict__ A1, const float* __restrict__ A2,
                                              int K1, int Ktot,
                                              const float* __restrict__ W, const float* __restrict__ bias,
                                              float* __restrict__ C, int N, int ldc) {
  __shared__ float As[32][68];  // stride 68: 16B-aligned rows for b128 reads; 4-way write conflict only
  __shared__ float Ws[32][64];
  int tid = threadIdx.x;
  int tx = tid & 15, ty = tid >> 4;
  int rowBase = blockIdx.x * 64, colBase = blockIdx.y * 64;
  float acc[4][4] = {{0.f}};

  int kk = tid & 31, rr = tid >> 5;   // A-tile load mapping
  int cc = tid & 63, kw = tid >> 6;   // W-tile load mapping

  for (int k0 = 0; k0 < Ktot; k0 += 32) {
    const float* Asrc = (k0 < K1) ? A1 : A2;
    int Ka   = (k0 < K1) ? K1 : (Ktot - K1);
    int kloc = (k0 < K1) ? k0 : (k0 - K1);
#pragma unroll
    for (int i = 0; i < 8; ++i) {
      int r = rr + i * 8;
      int grow = rowBase + r;
      As[kk][r] = (grow < N) ? Asrc[(size_t)grow * Ka + kloc + kk] : 0.f;
    }
#pragma unroll
    for (int i = 0; i < 8; ++i) {
      int k = kw + i * 4;
      Ws[k][cc] = W[(size_t)(k0 + k) * ldc + colBase + cc];
    }
    __syncthreads();
#pragma unroll
    for (int k2 = 0; k2 < 32; ++k2) {
      float4 a = *(const float4*)&As[k2][ty * 4];
      float4 w = *(const float4*)&Ws[k2][tx * 4];
      acc[0][0] = fmaf(a.x, w.x, acc[0][0]); acc[0][1] = fmaf(a.x, w.y, acc[0][1]);
      acc[0][2] = fmaf(a.x, w.z, acc[0][2]); acc[0][3] = fmaf(a.x, w.w, acc[0][3]);
      acc[1][0] = fmaf(a.y, w.x, acc[1][0]); acc[1][1] = fmaf(a.y, w.y, acc[1][1]);
      acc[1][2] = fmaf(a.y, w.z, acc[1][2]); acc[1][3] = fmaf(a.y, w.w, acc[1][3]);
      acc[2][0] = fmaf(a.z, w.x, acc[2][0]); acc[2][1] = fmaf(a.z, w.y, acc[2][1]);
      acc[2][2] = fmaf(a.z, w.z, acc[2][2]); acc[2][3] = fmaf(a.z, w.w, acc[2][3]);
      acc[3][0] = fmaf(a.w, w.x, acc[3][0]); acc[3][1] = fmaf(a.w, w.y, acc[3][1]);
      acc[3][2] = fmaf(a.w, w.z, acc[3][2]); acc[3][3] = fmaf(a.w, w.w, acc[3][3]);
    }
    __syncthreads();
  }

#pragma unroll
  for (int i = 0; i < 4; ++i) {
    int row = rowBase + ty * 4 + i;
    if (row < N) {
      float4 o = make_float4(acc[i][0], acc[i][1], acc[i][2], acc[i][3]);
      if (HASBIAS) {
        const float4 b = *(const float4*)&bias[colBase + tx * 4];
        o.x += b.x; o.y += b.y; o.z += b.z; o.w += b.w;
      }
      if (RELU) {
        o.x = fmaxf(o.x, 0.f); o.y = fmaxf(o.y, 0.f);
        o.z = fmaxf(o.z, 0.f); o.w = fmaxf(o.w, 0.f);
      }
      *(float4*)&C[(size_t)row * ldc + colBase + tx * 4] = o;
    }
  }
}

// ---------------- head: out[N x 8] = h[N x 128] @ Wc[128 x 8] + bc ----------------
__global__ __launch_bounds__(256) void head_k(const float* __restrict__ h, const float* __restrict__ Wc,
                                              const float* __restrict__ bc, float* __restrict__ out, int n) {
  __shared__ float Ws[1024];
  __shared__ float bs[8];
  for (int i = threadIdx.x; i < 1024; i += 256) Ws[i] = Wc[i];
  if (threadIdx.x < 8) bs[threadIdx.x] = bc[threadIdx.x];
  __syncthreads();
  int j = threadIdx.x & 7, il = threadIdx.x >> 3;
  int row = blockIdx.x * 32 + il;
  if (row >= n) return;
  const float4* hr = (const float4*)&h[(size_t)row * 128];
  float acc = bs[j];
#pragma unroll
  for (int d4 = 0; d4 < 32; ++d4) {
    float4 v = hr[d4];
    int d = d4 * 4;
    acc = fmaf(v.x, Ws[(d + 0) * 8 + j], acc);
    acc = fmaf(v.y, Ws[(d + 1) * 8 + j], acc);
    acc = fmaf(v.z, Ws[(d + 2) * 8 + j], acc);
    acc = fmaf(v.w, Ws[(d + 3) * 8 + j], acc);
  }
  out[(size_t)row * 8 + j] = acc;
}

// ---------------- host ----------------
extern "C" void kernel_launch(void* const* d_in, const int* in_sizes, int n_in,
                              void* d_out, int out_size, void* d_ws, size_t ws_size,
                              hipStream_t stream) {
  const float* x      = (const float*)d_in[0];
  const int*   ei     = (const int*)d_in[1];   // [2][E] (harness materializes integers as int32)
  const float* Wf_l   = (const float*)d_in[2];
  const float* bf     = (const float*)d_in[3];
  const float* Wf_r   = (const float*)d_in[4];
  const float* W0_l   = (const float*)d_in[5];
  const float* b0     = (const float*)d_in[6];
  const float* W0_r   = (const float*)d_in[7];
  const float* W1_l   = (const float*)d_in[8];
  const float* b1     = (const float*)d_in[9];
  const float* W1_r   = (const float*)d_in[10];
  const float* W_lin  = (const float*)d_in[11];
  const float* b_lin  = (const float*)d_in[12];
  const float* W_lin2 = (const float*)d_in[13];
  const float* b_lin2 = (const float*)d_in[14];
  float* out = (float*)d_out;

  const int N = in_sizes[0] / 64;   // 50000
  const int E = in_sizes[1] / 2;    // 800000
  const int* e_src = ei;
  const int* e_tgt = ei + E;

  // workspace carve (256B aligned)
  size_t off = 0;
  char* base = (char*)d_ws;
  auto carve = [&](size_t bytes) -> void* {
    void* p = base + off;
    off += (bytes + 255) & ~(size_t)255;
    return p;
  };
  int*   row_ptr = (int*)carve((size_t)(N + 1) * 4);
  int*   cursor  = (int*)carve((size_t)N * 4);       // also used as cnt
  int*   bsum    = (int*)carve(64 * 4);
  int*   boff    = (int*)carve(64 * 4);
  int*   srcs    = (int*)carve((size_t)E * 4);
  float* Wf_cat  = (float*)carve(128 * 256 * 4);     // [Wf_l; Wf_r] row-concat
  float* Wcat2   = (float*)carve(256 * 256 * 4);     // [W0_l | W0_r] col-concat
  float* Wcat3   = (float*)carve(128 * 256 * 4);     // [W1_l | W1_r]
  float* Wcomb   = (float*)carve(1024 * 4);
  float* bcomb   = (float*)carve(8 * 4);
  float* m       = (float*)carve((size_t)N * 64 * 4);
  float* h1      = (float*)carve((size_t)N * 256 * 4);
  float* C23     = (float*)carve((size_t)N * 256 * 4);  // C2 then C3
  float* h23     = (float*)carve((size_t)N * 128 * 4);  // h2 then h3
  (void)ws_size; (void)n_in; (void)out_size;

  const int nbE   = (E + 255) / 256;         // 3125
  const int nbScn = (N + 1023) / 1024;       // 49

  // CSR build
  hipMemsetAsync(cursor, 0, (size_t)N * 4, stream);
  count_k<<<nbE, 256, 0, stream>>>(e_tgt, cursor, E);
  scan_block_k<<<nbScn, 1024, 0, stream>>>(cursor, row_ptr, bsum, N);
  scan_bsum_k<<<1, 64, 0, stream>>>(bsum, boff, row_ptr, nbScn, N);
  scan_add_k<<<nbScn, 1024, 0, stream>>>(row_ptr, cursor, boff, N);
  fill_k<<<nbE, 256, 0, stream>>>(e_src, e_tgt, cursor, srcs, E);

  // weight packing + head fold
  pack_rows_k<<<(2 * 64 * 256 + 255) / 256, 256, 0, stream>>>(Wf_l, Wf_r, Wf_cat, 64 * 256);
  pack_cols_k<<<(256 * 256 + 255) / 256, 256, 0, stream>>>(W0_l, W0_r, Wcat2, 256, 128);
  pack_cols_k<<<(128 * 256 + 255) / 256, 256, 0, stream>>>(W1_l, W1_r, Wcat3, 128, 128);
  comb_k<<<4, 256, 0, stream>>>(W_lin, b_lin, W_lin2, b_lin2, Wcomb, bcomb);

  const int nbAgg  = (N + 3) / 4;            // 12500
  const dim3 gemmGrid((N + 63) / 64, 4);     // 782 x 4 (Dout=256)

  // Layer 1: aggregate (D=64) then dual-A GEMM with bias+relu
  agg_mean64_k<<<nbAgg, 256, 0, stream>>>(x, row_ptr, srcs, m, N);
  gemm_k<1, 1><<<gemmGrid, 256, 0, stream>>>(m, x, 64, 128, Wf_cat, bf, h1, N, 256);

  // Layer 2: transform-first (K=256 -> y|z in 256 cols), aggregate+residual+bias+relu
  gemm_k<0, 0><<<gemmGrid, 256, 0, stream>>>(h1, h1, 256, 256, Wcat2, nullptr, C23, N, 256);
  agg_mean128_k<<<nbAgg, 256, 0, stream>>>(C23, b0, row_ptr, srcs, h23, N);

  // Layer 3
  gemm_k<0, 0><<<gemmGrid, 256, 0, stream>>>(h23, h23, 128, 128, Wcat3, nullptr, C23, N, 256);
  agg_mean128_k<<<nbAgg, 256, 0, stream>>>(C23, b1, row_ptr, srcs, h23, N);

  // head
  head_k<<<(N + 31) / 32, 256, 0, stream>>>(h23, Wcomb, bcomb, out, N);
}

// Round 2
// 677.333 us; speedup vs baseline: 1.0049x; 1.0049x over previous
//
#include <hip/hip_runtime.h>

// GraphSAGE 3-layer + head, fp32, MI355X.
// R1: GEMM upgraded to BM=128 BN=128 BK=32, 8x8 per-thread micro-tile.
//   Theory: 4x4 tile was issue-bound (FMA only ~60% of issued VALU, 33% of fp32 peak);
//   8x8 quadruples FMA per k-step per thread. Predicted L2 GEMM 127 -> ~60 us.
// Structure:
//   CSR build (count/scan/fill) once per call
//   L1: agg(x, D=64) -> m; h1 = relu([m|x] @ [Wf_l;Wf_r] + bf)        (dual-A GEMM, K=128, Dout=256)
//   L2: C2 = h1 @ [W0_l|W0_r] (K=256, Dout=256); h2 = relu(mean(y2)+z2+b0)
//   L3: C3 = h2 @ [W1_l|W1_r] (K=128, Dout=256); h3 = relu(mean(y3)+z3+b1)
//   head: out = h3 @ (W_lin@W_lin2) + (b_lin@W_lin2 + b_lin2)

// ---------------- CSR build ----------------
__global__ __launch_bounds__(256) void count_k(const int* __restrict__ tgt, int* __restrict__ cnt, int E) {
  int e = blockIdx.x * 256 + threadIdx.x;
  if (e < E) atomicAdd(&cnt[tgt[e]], 1);
}

__global__ __launch_bounds__(1024) void scan_block_k(const int* __restrict__ cnt, int* __restrict__ row_ptr,
                                                     int* __restrict__ bsum, int N) {
  __shared__ int sh[1024];
  int tid = threadIdx.x;
  int i = blockIdx.x * 1024 + tid;
  int v = (i < N) ? cnt[i] : 0;
  int val = v;
  sh[tid] = val;
  __syncthreads();
  for (int off = 1; off < 1024; off <<= 1) {
    int t = (tid >= off) ? sh[tid - off] : 0;
    __syncthreads();
    val += t;
    sh[tid] = val;
    __syncthreads();
  }
  if (i < N) row_ptr[i] = val - v;      // exclusive
  if (tid == 1023) bsum[blockIdx.x] = val;
}

__global__ void scan_bsum_k(const int* __restrict__ bsum, int* __restrict__ boff,
                            int* __restrict__ row_ptr, int nb, int N) {
  if (threadIdx.x == 0 && blockIdx.x == 0) {
    int run = 0;
    for (int b = 0; b < nb; ++b) { boff[b] = run; run += bsum[b]; }
    row_ptr[N] = run;
  }
}

__global__ __launch_bounds__(1024) void scan_add_k(int* __restrict__ row_ptr, int* __restrict__ cursor,
                                                   const int* __restrict__ boff, int N) {
  int i = blockIdx.x * 1024 + threadIdx.x;
  if (i < N) {
    int v = row_ptr[i] + boff[blockIdx.x];
    row_ptr[i] = v;
    cursor[i] = v;
  }
}

__global__ __launch_bounds__(256) void fill_k(const int* __restrict__ src, const int* __restrict__ tgt,
                                              int* __restrict__ cursor, int* __restrict__ srcs, int E) {
  int e = blockIdx.x * 256 + threadIdx.x;
  if (e < E) {
    int pos = atomicAdd(&cursor[tgt[e]], 1);
    srcs[pos] = src[e];
  }
}

// ---------------- weight packing ----------------
__global__ __launch_bounds__(256) void pack_rows_k(const float* __restrict__ Wl, const float* __restrict__ Wr,
                                                   float* __restrict__ dst, int half) {
  int t = blockIdx.x * 256 + threadIdx.x;
  if (t < 2 * half) dst[t] = (t < half) ? Wl[t] : Wr[t - half];
}

__global__ __launch_bounds__(256) void pack_cols_k(const float* __restrict__ Wl, const float* __restrict__ Wr,
                                                   float* __restrict__ dst, int K, int H) {
  int t = blockIdx.x * 256 + threadIdx.x;
  if (t >= K * 2 * H) return;
  int k = t / (2 * H);
  int c = t - k * 2 * H;
  dst[t] = (c < H) ? Wl[k * H + c] : Wr[k * H + (c - H)];
}

// Wc[128x8] = W_lin(128x128) @ W_lin2(128x8); bc[8] = b_lin @ W_lin2 + b_lin2
__global__ __launch_bounds__(256) void comb_k(const float* __restrict__ Wlin, const float* __restrict__ blin,
                                              const float* __restrict__ Wlin2, const float* __restrict__ blin2,
                                              float* __restrict__ Wc, float* __restrict__ bc) {
  int t = blockIdx.x * 256 + threadIdx.x;
  if (t < 1024) {
    int i = t >> 3, j = t & 7;
    float acc = 0.f;
    for (int k = 0; k < 128; ++k) acc = fmaf(Wlin[i * 128 + k], Wlin2[k * 8 + j], acc);
    Wc[t] = acc;
  }
  if (t < 8) {
    float acc = blin2[t];
    for (int k = 0; k < 128; ++k) acc = fmaf(blin[k], Wlin2[k * 8 + t], acc);
    bc[t] = acc;
  }
}

// ---------------- aggregation ----------------
__global__ __launch_bounds__(256) void agg_mean64_k(const float* __restrict__ x, const int* __restrict__ rp,
                                                    const int* __restrict__ srcs, float* __restrict__ m, int n) {
  int w = threadIdx.x >> 6, lane = threadIdx.x & 63;
  int node = blockIdx.x * 4 + w;
  if (node >= n) return;
  int s0 = rp[node], s1 = rp[node + 1];
  float sum = 0.f;
  for (int e = s0; e < s1; ++e) {
    int s = srcs[e];
    sum += x[(size_t)s * 64 + lane];
  }
  int deg = s1 - s0;
  float inv = 1.f / (float)(deg > 0 ? deg : 1);
  m[(size_t)node * 64 + lane] = sum * inv;
}

__global__ __launch_bounds__(256) void agg_mean128_k(const float* __restrict__ C, const float* __restrict__ bias,
                                                     const int* __restrict__ rp, const int* __restrict__ srcs,
                                                     float* __restrict__ hout, int n) {
  int w = threadIdx.x >> 6, lane = threadIdx.x & 63;
  int node = blockIdx.x * 4 + w;
  if (node >= n) return;
  int s0 = rp[node], s1 = rp[node + 1];
  int d = lane * 2;
  float sx = 0.f, sy = 0.f;
  for (int e = s0; e < s1; ++e) {
    int s = srcs[e];
    const float2 v = *(const float2*)&C[(size_t)s * 256 + d];
    sx += v.x; sy += v.y;
  }
  int deg = s1 - s0;
  float inv = 1.f / (float)(deg > 0 ? deg : 1);
  float2 z = *(const float2*)&C[(size_t)node * 256 + 128 + d];
  float2 b = *(const float2*)&bias[d];
  float ox = fmaxf(fmaf(sx, inv, z.x + b.x), 0.f);
  float oy = fmaxf(fmaf(sy, inv, z.y + b.y), 0.f);
  *(float2*)&hout[(size_t)node * 128 + d] = make_float2(ox, oy);
}

// ---------------- GEMM: C[N x ldc tile] = [A1|A2] @ W (+bias)(relu) ----------------
// BM=128 BN=128 BK=32, 256 threads, 8x8 per thread.
// A1: N x K1, A2: N x (Ktot-K1), both row-major. W: Ktot x ldc row-major (packed).
// As transposed [k][row] stride 132 (132 mod 32 = 4 -> write conflicts <= 4-way, a-reads broadcast).
template <int RELU, int HASBIAS>
__global__ __launch_bounds__(256) void gemm_k(const float* __restrict__ A1, const float* __restrict__ A2,
                                              int K1, int Ktot,
                                              const float* __restrict__ W, const float* __restrict__ bias,
                                              float* __restrict__ C, int N, int ldc) {
  __shared__ float As[32][132];
  __shared__ float Ws[32][128];
  int tid = threadIdx.x;
  int tx = tid & 15, ty = tid >> 4;       // micro-tile coords: cols tx*8, rows ty*8
  int rowBase = blockIdx.x * 128, colBase = blockIdx.y * 128;
  float acc[8][8] = {{0.f}};

  int ca = tid & 31, ra = tid >> 5;       // A staging: col (k within tile), row-group
  int cw = (tid & 31) * 4, rw = tid >> 5; // W staging: col4, k-row-group

  for (int k0 = 0; k0 < Ktot; k0 += 32) {
    const float* Asrc = (k0 < K1) ? A1 : A2;
    int Ka   = (k0 < K1) ? K1 : (Ktot - K1);
    int kloc = (k0 < K1) ? k0 : (k0 - K1);
#pragma unroll
    for (int i = 0; i < 16; ++i) {
      int r = ra + i * 8;
      int grow = rowBase + r;
      As[ca][r] = (grow < N) ? Asrc[(size_t)grow * Ka + kloc + ca] : 0.f;
    }
#pragma unroll
    for (int i = 0; i < 4; ++i) {
      int k = rw + i * 8;
      *(float4*)&Ws[k][cw] = *(const float4*)&W[(size_t)(k0 + k) * ldc + colBase + cw];
    }
    __syncthreads();
#pragma unroll 8
    for (int k2 = 0; k2 < 32; ++k2) {
      float4 a0 = *(const float4*)&As[k2][ty * 8];
      float4 a1 = *(const float4*)&As[k2][ty * 8 + 4];
      float4 w0 = *(const float4*)&Ws[k2][tx * 8];
      float4 w1 = *(const float4*)&Ws[k2][tx * 8 + 4];
      float av[8] = {a0.x, a0.y, a0.z, a0.w, a1.x, a1.y, a1.z, a1.w};
      float wv[8] = {w0.x, w0.y, w0.z, w0.w, w1.x, w1.y, w1.z, w1.w};
#pragma unroll
      for (int i = 0; i < 8; ++i)
#pragma unroll
        for (int j = 0; j < 8; ++j)
          acc[i][j] = fmaf(av[i], wv[j], acc[i][j]);
    }
    __syncthreads();
  }

#pragma unroll
  for (int i = 0; i < 8; ++i) {
    int row = rowBase + ty * 8 + i;
    if (row < N) {
      float4 o0 = make_float4(acc[i][0], acc[i][1], acc[i][2], acc[i][3]);
      float4 o1 = make_float4(acc[i][4], acc[i][5], acc[i][6], acc[i][7]);
      if (HASBIAS) {
        const float4 b0v = *(const float4*)&bias[colBase + tx * 8];
        const float4 b1v = *(const float4*)&bias[colBase + tx * 8 + 4];
        o0.x += b0v.x; o0.y += b0v.y; o0.z += b0v.z; o0.w += b0v.w;
        o1.x += b1v.x; o1.y += b1v.y; o1.z += b1v.z; o1.w += b1v.w;
      }
      if (RELU) {
        o0.x = fmaxf(o0.x, 0.f); o0.y = fmaxf(o0.y, 0.f);
        o0.z = fmaxf(o0.z, 0.f); o0.w = fmaxf(o0.w, 0.f);
        o1.x = fmaxf(o1.x, 0.f); o1.y = fmaxf(o1.y, 0.f);
        o1.z = fmaxf(o1.z, 0.f); o1.w = fmaxf(o1.w, 0.f);
      }
      *(float4*)&C[(size_t)row * ldc + colBase + tx * 8] = o0;
      *(float4*)&C[(size_t)row * ldc + colBase + tx * 8 + 4] = o1;
    }
  }
}

// ---------------- head: out[N x 8] = h[N x 128] @ Wc[128 x 8] + bc ----------------
__global__ __launch_bounds__(256) void head_k(const float* __restrict__ h, const float* __restrict__ Wc,
                                              const float* __restrict__ bc, float* __restrict__ out, int n) {
  __shared__ float Ws[1024];
  __shared__ float bs[8];
  for (int i = threadIdx.x; i < 1024; i += 256) Ws[i] = Wc[i];
  if (threadIdx.x < 8) bs[threadIdx.x] = bc[threadIdx.x];
  __syncthreads();
  int j = threadIdx.x & 7, il = threadIdx.x >> 3;
  int row = blockIdx.x * 32 + il;
  if (row >= n) return;
  const float4* hr = (const float4*)&h[(size_t)row * 128];
  float acc = bs[j];
#pragma unroll
  for (int d4 = 0; d4 < 32; ++d4) {
    float4 v = hr[d4];
    int d = d4 * 4;
    acc = fmaf(v.x, Ws[(d + 0) * 8 + j], acc);
    acc = fmaf(v.y, Ws[(d + 1) * 8 + j], acc);
    acc = fmaf(v.z, Ws[(d + 2) * 8 + j], acc);
    acc = fmaf(v.w, Ws[(d + 3) * 8 + j], acc);
  }
  out[(size_t)row * 8 + j] = acc;
}

// ---------------- host ----------------
extern "C" void kernel_launch(void* const* d_in, const int* in_sizes, int n_in,
                              void* d_out, int out_size, void* d_ws, size_t ws_size,
                              hipStream_t stream) {
  const float* x      = (const float*)d_in[0];
  const int*   ei     = (const int*)d_in[1];
  const float* Wf_l   = (const float*)d_in[2];
  const float* bf     = (const float*)d_in[3];
  const float* Wf_r   = (const float*)d_in[4];
  const float* W0_l   = (const float*)d_in[5];
  const float* b0     = (const float*)d_in[6];
  const float* W0_r   = (const float*)d_in[7];
  const float* W1_l   = (const float*)d_in[8];
  const float* b1     = (const float*)d_in[9];
  const float* W1_r   = (const float*)d_in[10];
  const float* W_lin  = (const float*)d_in[11];
  const float* b_lin  = (const float*)d_in[12];
  const float* W_lin2 = (const float*)d_in[13];
  const float* b_lin2 = (const float*)d_in[14];
  float* out = (float*)d_out;

  const int N = in_sizes[0] / 64;   // 50000
  const int E = in_sizes[1] / 2;    // 800000
  const int* e_src = ei;
  const int* e_tgt = ei + E;

  size_t off = 0;
  char* base = (char*)d_ws;
  auto carve = [&](size_t bytes) -> void* {
    void* p = base + off;
    off += (bytes + 255) & ~(size_t)255;
    return p;
  };
  int*   row_ptr = (int*)carve((size_t)(N + 1) * 4);
  int*   cursor  = (int*)carve((size_t)N * 4);
  int*   bsum    = (int*)carve(64 * 4);
  int*   boff    = (int*)carve(64 * 4);
  int*   srcs    = (int*)carve((size_t)E * 4);
  float* Wf_cat  = (float*)carve(128 * 256 * 4);
  float* Wcat2   = (float*)carve(256 * 256 * 4);
  float* Wcat3   = (float*)carve(128 * 256 * 4);
  float* Wcomb   = (float*)carve(1024 * 4);
  float* bcomb   = (float*)carve(8 * 4);
  float* m       = (float*)carve((size_t)N * 64 * 4);
  float* h1      = (float*)carve((size_t)N * 256 * 4);
  float* C23     = (float*)carve((size_t)N * 256 * 4);
  float* h23     = (float*)carve((size_t)N * 128 * 4);
  (void)ws_size; (void)n_in; (void)out_size;

  const int nbE   = (E + 255) / 256;
  const int nbScn = (N + 1023) / 1024;

  // CSR build
  hipMemsetAsync(cursor, 0, (size_t)N * 4, stream);
  count_k<<<nbE, 256, 0, stream>>>(e_tgt, cursor, E);
  scan_block_k<<<nbScn, 1024, 0, stream>>>(cursor, row_ptr, bsum, N);
  scan_bsum_k<<<1, 64, 0, stream>>>(bsum, boff, row_ptr, nbScn, N);
  scan_add_k<<<nbScn, 1024, 0, stream>>>(row_ptr, cursor, boff, N);
  fill_k<<<nbE, 256, 0, stream>>>(e_src, e_tgt, cursor, srcs, E);

  // weight packing + head fold
  pack_rows_k<<<(2 * 64 * 256 + 255) / 256, 256, 0, stream>>>(Wf_l, Wf_r, Wf_cat, 64 * 256);
  pack_cols_k<<<(256 * 256 + 255) / 256, 256, 0, stream>>>(W0_l, W0_r, Wcat2, 256, 128);
  pack_cols_k<<<(128 * 256 + 255) / 256, 256, 0, stream>>>(W1_l, W1_r, Wcat3, 128, 128);
  comb_k<<<4, 256, 0, stream>>>(W_lin, b_lin, W_lin2, b_lin2, Wcomb, bcomb);

  const int nbAgg = (N + 3) / 4;
  const dim3 gemmGrid((N + 127) / 128, 2);   // 391 x 2 (Dout=256, BN=128)

  // Layer 1
  agg_mean64_k<<<nbAgg, 256, 0, stream>>>(x, row_ptr, srcs, m, N);
  gemm_k<1, 1><<<gemmGrid, 256, 0, stream>>>(m, x, 64, 128, Wf_cat, bf, h1, N, 256);

  // Layer 2
  gemm_k<0, 0><<<gemmGrid, 256, 0, stream>>>(h1, h1, 256, 256, Wcat2, nullptr, C23, N, 256);
  agg_mean128_k<<<nbAgg, 256, 0, stream>>>(C23, b0, row_ptr, srcs, h23, N);

  // Layer 3
  gemm_k<0, 0><<<gemmGrid, 256, 0, stream>>>(h23, h23, 128, 128, Wcat3, nullptr, C23, N, 256);
  agg_mean128_k<<<nbAgg, 256, 0, stream>>>(C23, b1, row_ptr, srcs, h23, N);

  // head
  head_k<<<(N + 31) / 32, 256, 0, stream>>>(h23, Wcomb, bcomb, out, N);
}

// Round 3
// 536.892 us; speedup vs baseline: 1.2677x; 1.2616x over previous
//
#include <hip/hip_runtime.h>

// GraphSAGE 3-layer + head, MI355X.
// R2: GEMMs moved to bf16 MFMA (16x16x32), A in bf16 (1 term), W in bf16 hi+lo (2 terms).
//   fp32 vector GEMM plateaued at ~53 TF (latency-bound at 3 blocks/CU); MFMA path
//   targets ~500 TF on the m93 structure. Accuracy: output threshold is 2% relative
//   (2.6e-5 abs vs 1.3e-3 ref absmax); bf16-A error est. ~3e-6 at output.
// Structure:
//   CSR build; x->bf16; weights pre-transposed n-major + hi/lo split; head folded.
//   L1: agg64(x)->mb(bf16); h1b = relu_bf16([mb|xb] @ [Wf_l;Wf_r] + bf)   K'=4x64
//   L2: C2 = h1b @ [W0_l|W0_r] (K'=2x256); h2b = bf16(relu(mean(y)+z+b0))
//   L3: C3 = h2b @ [W1_l|W1_r] (K'=2x128); h3  = relu(mean(y)+z+b1) fp32
//   head: out = h3 @ (W_lin@W_lin2) + folded bias

typedef __attribute__((ext_vector_type(8))) short bf16x8;
typedef __attribute__((ext_vector_type(4))) float f32x4;

struct Seg { const unsigned short* A; const unsigned short* W; int lda; int ldw; int K; };
struct Segs { Seg s[4]; int n; };

__device__ __forceinline__ unsigned short f2bf(float x) {
  unsigned u = __float_as_uint(x);
  u += 0x7FFF + ((u >> 16) & 1);   // RNE (no NaN inputs here)
  return (unsigned short)(u >> 16);
}

// ---------------- CSR build ----------------
__global__ __launch_bounds__(256) void count_k(const int* __restrict__ tgt, int* __restrict__ cnt, int E) {
  int e = blockIdx.x * 256 + threadIdx.x;
  if (e < E) atomicAdd(&cnt[tgt[e]], 1);
}

__global__ __launch_bounds__(1024) void scan_block_k(const int* __restrict__ cnt, int* __restrict__ row_ptr,
                                                     int* __restrict__ bsum, int N) {
  __shared__ int sh[1024];
  int tid = threadIdx.x;
  int i = blockIdx.x * 1024 + tid;
  int v = (i < N) ? cnt[i] : 0;
  int val = v;
  sh[tid] = val;
  __syncthreads();
  for (int off = 1; off < 1024; off <<= 1) {
    int t = (tid >= off) ? sh[tid - off] : 0;
    __syncthreads();
    val += t;
    sh[tid] = val;
    __syncthreads();
  }
  if (i < N) row_ptr[i] = val - v;
  if (tid == 1023) bsum[blockIdx.x] = val;
}

__global__ void scan_bsum_k(const int* __restrict__ bsum, int* __restrict__ boff,
                            int* __restrict__ row_ptr, int nb, int N) {
  if (threadIdx.x == 0 && blockIdx.x == 0) {
    int run = 0;
    for (int b = 0; b < nb; ++b) { boff[b] = run; run += bsum[b]; }
    row_ptr[N] = run;
  }
}

__global__ __launch_bounds__(1024) void scan_add_k(int* __restrict__ row_ptr, int* __restrict__ cursor,
                                                   const int* __restrict__ boff, int N) {
  int i = blockIdx.x * 1024 + threadIdx.x;
  if (i < N) {
    int v = row_ptr[i] + boff[blockIdx.x];
    row_ptr[i] = v;
    cursor[i] = v;
  }
}

__global__ __launch_bounds__(256) void fill_k(const int* __restrict__ src, const int* __restrict__ tgt,
                                              int* __restrict__ cursor, int* __restrict__ srcs, int E) {
  int e = blockIdx.x * 256 + threadIdx.x;
  if (e < E) {
    int pos = atomicAdd(&cursor[tgt[e]], 1);
    srcs[pos] = src[e];
  }
}

// ---------------- conversions / weight packing ----------------
__global__ __launch_bounds__(256) void conv_bf16_k(const float* __restrict__ x, unsigned short* __restrict__ xb, int n4) {
  int i = blockIdx.x * 256 + threadIdx.x;
  if (i < n4) {
    float4 v = ((const float4*)x)[i];
    ushort2 a = make_ushort2(f2bf(v.x), f2bf(v.y));
    ushort2 b = make_ushort2(f2bf(v.z), f2bf(v.w));
    ((ushort2*)xb)[i * 2] = a;
    ((ushort2*)xb)[i * 2 + 1] = b;
  }
}

__device__ __forceinline__ void split_store(float v, unsigned short* hi, unsigned short* lo, int idx) {
  unsigned short h = f2bf(v);
  float hf = __uint_as_float(((unsigned)h) << 16);
  hi[idx] = h;
  lo[idx] = f2bf(v - hf);
}

// k-split pack: Wt[n][k] (256 x Ktot), k<Kh from Wa[k*256+n], else Wb[(k-Kh)*256+n]
__global__ __launch_bounds__(256) void pack_ksplit_k(const float* __restrict__ Wa, const float* __restrict__ Wb,
                                                     unsigned short* __restrict__ Whi, unsigned short* __restrict__ Wlo,
                                                     int Kh, int Ktot) {
  int t = blockIdx.x * 256 + threadIdx.x;
  if (t >= 256 * Ktot) return;
  int n = t / Ktot, k = t - n * Ktot;
  float v = (k < Kh) ? Wa[k * 256 + n] : Wb[(k - Kh) * 256 + n];
  split_store(v, Whi, Wlo, t);
}

// n-split pack: Wt[n][k] (256 x K), n<128 from Wa[k*128+n], else Wb[k*128+(n-128)]
__global__ __launch_bounds__(256) void pack_nsplit_k(const float* __restrict__ Wa, const float* __restrict__ Wb,
                                                     unsigned short* __restrict__ Whi, unsigned short* __restrict__ Wlo,
                                                     int K) {
  int t = blockIdx.x * 256 + threadIdx.x;
  if (t >= 256 * K) return;
  int n = t / K, k = t - n * K;
  float v = (n < 128) ? Wa[k * 128 + n] : Wb[k * 128 + (n - 128)];
  split_store(v, Whi, Wlo, t);
}

// Wc[128x8] = W_lin @ W_lin2; bc[8] = b_lin @ W_lin2 + b_lin2
__global__ __launch_bounds__(256) void comb_k(const float* __restrict__ Wlin, const float* __restrict__ blin,
                                              const float* __restrict__ Wlin2, const float* __restrict__ blin2,
                                              float* __restrict__ Wc, float* __restrict__ bc) {
  int t = blockIdx.x * 256 + threadIdx.x;
  if (t < 1024) {
    int i = t >> 3, j = t & 7;
    float acc = 0.f;
    for (int k = 0; k < 128; ++k) acc = fmaf(Wlin[i * 128 + k], Wlin2[k * 8 + j], acc);
    Wc[t] = acc;
  }
  if (t < 8) {
    float acc = blin2[t];
    for (int k = 0; k < 128; ++k) acc = fmaf(blin[k], Wlin2[k * 8 + t], acc);
    bc[t] = acc;
  }
}

// ---------------- aggregation ----------------
// wave per node, D=64; writes bf16 mean
__global__ __launch_bounds__(256) void agg_mean64_k(const float* __restrict__ x, const int* __restrict__ rp,
                                                    const int* __restrict__ srcs, unsigned short* __restrict__ mb, int n) {
  int w = threadIdx.x >> 6, lane = threadIdx.x & 63;
  int node = blockIdx.x * 4 + w;
  if (node >= n) return;
  int s0 = rp[node], s1 = rp[node + 1];
  float sum = 0.f;
  for (int e = s0; e < s1; ++e) {
    int s = srcs[e];
    sum += x[(size_t)s * 64 + lane];
  }
  int deg = s1 - s0;
  float inv = 1.f / (float)(deg > 0 ? deg : 1);
  mb[(size_t)node * 64 + lane] = f2bf(sum * inv);
}

// wave per node, D=128 (float2/lane). C: Npad x 256 fp32, cols 0..127=y, 128..255=z.
// OUTBF16: hout is ushort (N x 128 bf16); else float (N x 128).
template <int OUTBF16>
__global__ __launch_bounds__(256) void agg_mean128_k(const float* __restrict__ C, const float* __restrict__ bias,
                                                     const int* __restrict__ rp, const int* __restrict__ srcs,
                                                     void* __restrict__ hout, int n) {
  int w = threadIdx.x >> 6, lane = threadIdx.x & 63;
  int node = blockIdx.x * 4 + w;
  if (node >= n) return;
  int s0 = rp[node], s1 = rp[node + 1];
  int d = lane * 2;
  float sx = 0.f, sy = 0.f;
  for (int e = s0; e < s1; ++e) {
    int s = srcs[e];
    const float2 v = *(const float2*)&C[(size_t)s * 256 + d];
    sx += v.x; sy += v.y;
  }
  int deg = s1 - s0;
  float inv = 1.f / (float)(deg > 0 ? deg : 1);
  float2 z = *(const float2*)&C[(size_t)node * 256 + 128 + d];
  float2 b = *(const float2*)&bias[d];
  float ox = fmaxf(fmaf(sx, inv, z.x + b.x), 0.f);
  float oy = fmaxf(fmaf(sy, inv, z.y + b.y), 0.f);
  if (OUTBF16) {
    ((ushort2*)hout)[((size_t)node * 128 + d) / 2] = make_ushort2(f2bf(ox), f2bf(oy));
  } else {
    *(float2*)&((float*)hout)[(size_t)node * 128 + d] = make_float2(ox, oy);
  }
}

// ---------------- MFMA GEMM ----------------
// Block tile 128x128, 4 waves (2x2), each wave 64x64 via 4x4 frags of 16x16x32 bf16 MFMA.
// A: list of K-segments (bf16, row-major, lda). W: bf16, n-major [n][k] with row stride ldw.
// All row dims padded to Npad -> no bounds checks.
// MODE 0: C fp32 out (no bias). MODE 1: bias+relu -> bf16 out.
template <int MODE>
__global__ __launch_bounds__(256) void gemm_mfma_k(Segs segs, const float* __restrict__ bias,
                                                   float* __restrict__ C, unsigned short* __restrict__ Ob,
                                                   int ldc) {
  __shared__ unsigned short Asl[128 * 32];
  __shared__ unsigned short Wsl[128 * 32];
  int tid = threadIdx.x;
  int lane = tid & 63, wave = tid >> 6;
  int wm = wave & 1, wn = wave >> 1;
  int rowBase = blockIdx.x * 128, colBase = blockIdx.y * 128;
  f32x4 acc[4][4] = {};

  // staging: 512 16B-chunks per tile; thread t covers chunks t and t+256
  int c0 = tid, c1 = tid + 256;
  int r0 = c0 >> 2, q0 = c0 & 3;
  int r1 = c1 >> 2, q1 = c1 & 3;
  int ml = lane & 15, qq = lane >> 4;

  for (int si = 0; si < segs.n; ++si) {
    const unsigned short* Aseg = segs.s[si].A;
    const unsigned short* Wseg = segs.s[si].W;
    int lda = segs.s[si].lda, ldw = segs.s[si].ldw, K = segs.s[si].K;
    for (int k0 = 0; k0 < K; k0 += 32) {
      uint4 av0 = *(const uint4*)&Aseg[(size_t)(rowBase + r0) * lda + k0 + q0 * 8];
      uint4 av1 = *(const uint4*)&Aseg[(size_t)(rowBase + r1) * lda + k0 + q1 * 8];
      uint4 wv0 = *(const uint4*)&Wseg[(size_t)(colBase + r0) * ldw + k0 + q0 * 8];
      uint4 wv1 = *(const uint4*)&Wseg[(size_t)(colBase + r1) * ldw + k0 + q1 * 8];
      __syncthreads();               // protect previous iteration's LDS reads
      *(uint4*)&Asl[c0 * 8] = av0;
      *(uint4*)&Asl[c1 * 8] = av1;
      *(uint4*)&Wsl[c0 * 8] = wv0;
      *(uint4*)&Wsl[c1 * 8] = wv1;
      __syncthreads();
      bf16x8 af[4], bw[4];
#pragma unroll
      for (int i = 0; i < 4; ++i) {
        af[i] = *(bf16x8*)&Asl[(wm * 64 + i * 16 + ml) * 32 + qq * 8];
        bw[i] = *(bf16x8*)&Wsl[(wn * 64 + i * 16 + ml) * 32 + qq * 8];
      }
#pragma unroll
      for (int mf = 0; mf < 4; ++mf)
#pragma unroll
        for (int nf = 0; nf < 4; ++nf)
          acc[mf][nf] = __builtin_amdgcn_mfma_f32_16x16x32_bf16(af[mf], bw[nf], acc[mf][nf], 0, 0, 0);
    }
  }

  if (MODE == 0) {
#pragma unroll
    for (int mf = 0; mf < 4; ++mf) {
      int row = rowBase + wm * 64 + mf * 16 + qq * 4;
#pragma unroll
      for (int nf = 0; nf < 4; ++nf) {
        int col = colBase + wn * 64 + nf * 16 + ml;
#pragma unroll
        for (int r = 0; r < 4; ++r)
          C[(size_t)(row + r) * ldc + col] = acc[mf][nf][r];
      }
    }
  } else {
    float bc4[4];
#pragma unroll
    for (int nf = 0; nf < 4; ++nf) bc4[nf] = bias[colBase + wn * 64 + nf * 16 + ml];
#pragma unroll
    for (int mf = 0; mf < 4; ++mf) {
      int row = rowBase + wm * 64 + mf * 16 + qq * 4;
#pragma unroll
      for (int nf = 0; nf < 4; ++nf) {
        int col = colBase + wn * 64 + nf * 16 + ml;
#pragma unroll
        for (int r = 0; r < 4; ++r) {
          float o = fmaxf(acc[mf][nf][r] + bc4[nf], 0.f);
          Ob[(size_t)(row + r) * ldc + col] = f2bf(o);
        }
      }
    }
  }
}

// ---------------- head: out[N x 8] = h[N x 128] @ Wc[128 x 8] + bc ----------------
__global__ __launch_bounds__(256) void head_k(const float* __restrict__ h, const float* __restrict__ Wc,
                                              const float* __restrict__ bc, float* __restrict__ out, int n) {
  __shared__ float Ws[1024];
  __shared__ float bs[8];
  for (int i = threadIdx.x; i < 1024; i += 256) Ws[i] = Wc[i];
  if (threadIdx.x < 8) bs[threadIdx.x] = bc[threadIdx.x];
  __syncthreads();
  int j = threadIdx.x & 7, il = threadIdx.x >> 3;
  int row = blockIdx.x * 32 + il;
  if (row >= n) return;
  const float4* hr = (const float4*)&h[(size_t)row * 128];
  float acc = bs[j];
#pragma unroll
  for (int d4 = 0; d4 < 32; ++d4) {
    float4 v = hr[d4];
    int d = d4 * 4;
    acc = fmaf(v.x, Ws[(d + 0) * 8 + j], acc);
    acc = fmaf(v.y, Ws[(d + 1) * 8 + j], acc);
    acc = fmaf(v.z, Ws[(d + 2) * 8 + j], acc);
    acc = fmaf(v.w, Ws[(d + 3) * 8 + j], acc);
  }
  out[(size_t)row * 8 + j] = acc;
}

// ---------------- host ----------------
extern "C" void kernel_launch(void* const* d_in, const int* in_sizes, int n_in,
                              void* d_out, int out_size, void* d_ws, size_t ws_size,
                              hipStream_t stream) {
  const float* x      = (const float*)d_in[0];
  const int*   ei     = (const int*)d_in[1];
  const float* Wf_l   = (const float*)d_in[2];
  const float* bf     = (const float*)d_in[3];
  const float* Wf_r   = (const float*)d_in[4];
  const float* W0_l   = (const float*)d_in[5];
  const float* b0     = (const float*)d_in[6];
  const float* W0_r   = (const float*)d_in[7];
  const float* W1_l   = (const float*)d_in[8];
  const float* b1     = (const float*)d_in[9];
  const float* W1_r   = (const float*)d_in[10];
  const float* W_lin  = (const float*)d_in[11];
  const float* b_lin  = (const float*)d_in[12];
  const float* W_lin2 = (const float*)d_in[13];
  const float* b_lin2 = (const float*)d_in[14];
  float* out = (float*)d_out;

  const int N = in_sizes[0] / 64;          // 50000
  const int E = in_sizes[1] / 2;           // 800000
  const int Npad = ((N + 127) / 128) * 128; // 50048 -> actually 50048? (N=50000 -> 391*128=50048)
  const int nblkM = Npad / 128;
  const int* e_src = ei;
  const int* e_tgt = ei + E;

  size_t off = 0;
  char* base = (char*)d_ws;
  auto carve = [&](size_t bytes) -> void* {
    void* p = base + off;
    off += (bytes + 255) & ~(size_t)255;
    return p;
  };
  int*   row_ptr = (int*)carve((size_t)(N + 1) * 4);
  int*   cursor  = (int*)carve((size_t)N * 4);
  int*   bsum    = (int*)carve(64 * 4);
  int*   boff    = (int*)carve(64 * 4);
  int*   srcs    = (int*)carve((size_t)E * 4);
  unsigned short* xb    = (unsigned short*)carve((size_t)Npad * 64 * 2);
  unsigned short* mb    = (unsigned short*)carve((size_t)Npad * 64 * 2);
  unsigned short* h1b   = (unsigned short*)carve((size_t)Npad * 256 * 2);
  unsigned short* h2b   = (unsigned short*)carve((size_t)Npad * 128 * 2);
  unsigned short* Wt1hi = (unsigned short*)carve(256 * 128 * 2);
  unsigned short* Wt1lo = (unsigned short*)carve(256 * 128 * 2);
  unsigned short* Wt2hi = (unsigned short*)carve(256 * 256 * 2);
  unsigned short* Wt2lo = (unsigned short*)carve(256 * 256 * 2);
  unsigned short* Wt3hi = (unsigned short*)carve(256 * 128 * 2);
  unsigned short* Wt3lo = (unsigned short*)carve(256 * 128 * 2);
  float* Wcomb = (float*)carve(1024 * 4);
  float* bcomb = (float*)carve(8 * 4);
  float* C23   = (float*)carve((size_t)Npad * 256 * 4);
  float* h23   = (float*)carve((size_t)N * 128 * 4);
  (void)ws_size; (void)n_in; (void)out_size;

  const int nbE   = (E + 255) / 256;
  const int nbScn = (N + 1023) / 1024;

  // CSR build
  hipMemsetAsync(cursor, 0, (size_t)N * 4, stream);
  count_k<<<nbE, 256, 0, stream>>>(e_tgt, cursor, E);
  scan_block_k<<<nbScn, 1024, 0, stream>>>(cursor, row_ptr, bsum, N);
  scan_bsum_k<<<1, 64, 0, stream>>>(bsum, boff, row_ptr, nbScn, N);
  scan_add_k<<<nbScn, 1024, 0, stream>>>(row_ptr, cursor, boff, N);
  fill_k<<<nbE, 256, 0, stream>>>(e_src, e_tgt, cursor, srcs, E);

  // conversions + packing + head fold
  conv_bf16_k<<<(N * 16 + 255) / 256, 256, 0, stream>>>(x, xb, N * 16);
  pack_ksplit_k<<<(256 * 128 + 255) / 256, 256, 0, stream>>>(Wf_l, Wf_r, Wt1hi, Wt1lo, 64, 128);
  pack_nsplit_k<<<(256 * 256 + 255) / 256, 256, 0, stream>>>(W0_l, W0_r, Wt2hi, Wt2lo, 256);
  pack_nsplit_k<<<(256 * 128 + 255) / 256, 256, 0, stream>>>(W1_l, W1_r, Wt3hi, Wt3lo, 128);
  comb_k<<<4, 256, 0, stream>>>(W_lin, b_lin, W_lin2, b_lin2, Wcomb, bcomb);

  const int nbAgg = (N + 3) / 4;
  const dim3 gemmGrid(nblkM, 2);

  // Layer 1: aggregate in D=64, then [mb|xb] @ Wt1(hi+lo), bias+relu -> bf16
  agg_mean64_k<<<nbAgg, 256, 0, stream>>>(x, row_ptr, srcs, mb, N);
  {
    Segs s;
    s.n = 4;
    s.s[0] = {mb, Wt1hi,      64, 128, 64};
    s.s[1] = {xb, Wt1hi + 64, 64, 128, 64};
    s.s[2] = {mb, Wt1lo,      64, 128, 64};
    s.s[3] = {xb, Wt1lo + 64, 64, 128, 64};
    gemm_mfma_k<1><<<gemmGrid, 256, 0, stream>>>(s, bf, nullptr, h1b, 256);
  }

  // Layer 2: h1b @ Wt2(hi+lo) -> C23 fp32; aggregate+residual -> h2b bf16
  {
    Segs s;
    s.n = 2;
    s.s[0] = {h1b, Wt2hi, 256, 256, 256};
    s.s[1] = {h1b, Wt2lo, 256, 256, 256};
    s.s[2] = {nullptr, nullptr, 0, 0, 0};
    s.s[3] = {nullptr, nullptr, 0, 0, 0};
    gemm_mfma_k<0><<<gemmGrid, 256, 0, stream>>>(s, nullptr, C23, nullptr, 256);
  }
  agg_mean128_k<1><<<nbAgg, 256, 0, stream>>>(C23, b0, row_ptr, srcs, h2b, N);

  // Layer 3: h2b @ Wt3(hi+lo) -> C23 fp32; aggregate+residual -> h23 fp32
  {
    Segs s;
    s.n = 2;
    s.s[0] = {h2b, Wt3hi, 128, 128, 128};
    s.s[1] = {h2b, Wt3lo, 128, 128, 128};
    s.s[2] = {nullptr, nullptr, 0, 0, 0};
    s.s[3] = {nullptr, nullptr, 0, 0, 0};
    gemm_mfma_k<0><<<gemmGrid, 256, 0, stream>>>(s, nullptr, C23, nullptr, 256);
  }
  agg_mean128_k<0><<<nbAgg, 256, 0, stream>>>(C23, b1, row_ptr, srcs, h23, N);

  // head
  head_k<<<(N + 31) / 32, 256, 0, stream>>>(h23, Wcomb, bcomb, out, N);
}

// Round 4
// 411.275 us; speedup vs baseline: 1.6550x; 1.3054x over previous
//
#include <hip/hip_runtime.h>
#include <hip/hip_fp16.h>

// GraphSAGE 3-layer + head, MI355X.
// R3: gathers moved to fp16 payloads (half bytes, half working set), 4-deep edge
//   unroll for MLP, head fused into layer-3 aggregation (shfl_xor butterfly).
//   GEMMs: bf16 MFMA 16x16x32, A bf16, W hi+lo split (unchanged from R2).
// Structure:
//   CSR build; x->xb(bf16 for GEMM)+xh(fp16 for gather); W pre-transposed+split.
//   L1: agg64(xh)->mb(bf16); h1b = relu_bf16([mb|xb] @ Wt1 + bf)
//   L2: yb|zb(fp16) = h1b @ Wt2; h2b = bf16(relu(mean(y)+z+b0))
//   L3: yb|zb(fp16) = h2b @ Wt3; fused: h3 = relu(mean+z+b1); out = h3 @ Wcomb + bcomb

typedef __attribute__((ext_vector_type(8))) short bf16x8;
typedef __attribute__((ext_vector_type(4))) float f32x4;

struct Seg { const unsigned short* A; const unsigned short* W; int lda; int ldw; int K; };
struct Segs { Seg s[4]; int n; };

__device__ __forceinline__ unsigned short f2bf(float x) {
  unsigned u = __float_as_uint(x);
  u += 0x7FFF + ((u >> 16) & 1);   // RNE
  return (unsigned short)(u >> 16);
}
__device__ __forceinline__ unsigned short f2h(float x) {
  return __half_as_ushort(__float2half(x));
}
__device__ __forceinline__ float2 ld_h2(const unsigned short* p, size_t idx) {
  unsigned uv = *(const unsigned*)(p + idx);
  __half2 h = *reinterpret_cast<__half2*>(&uv);
  return __half22float2(h);
}

// ---------------- CSR build ----------------
__global__ __launch_bounds__(256) void count_k(const int* __restrict__ tgt, int* __restrict__ cnt, int E) {
  int e = blockIdx.x * 256 + threadIdx.x;
  if (e < E) atomicAdd(&cnt[tgt[e]], 1);
}

__global__ __launch_bounds__(1024) void scan_block_k(const int* __restrict__ cnt, int* __restrict__ row_ptr,
                                                     int* __restrict__ bsum, int N) {
  __shared__ int sh[1024];
  int tid = threadIdx.x;
  int i = blockIdx.x * 1024 + tid;
  int v = (i < N) ? cnt[i] : 0;
  int val = v;
  sh[tid] = val;
  __syncthreads();
  for (int off = 1; off < 1024; off <<= 1) {
    int t = (tid >= off) ? sh[tid - off] : 0;
    __syncthreads();
    val += t;
    sh[tid] = val;
    __syncthreads();
  }
  if (i < N) row_ptr[i] = val - v;
  if (tid == 1023) bsum[blockIdx.x] = val;
}

__global__ void scan_bsum_k(const int* __restrict__ bsum, int* __restrict__ boff,
                            int* __restrict__ row_ptr, int nb, int N) {
  if (threadIdx.x == 0 && blockIdx.x == 0) {
    int run = 0;
    for (int b = 0; b < nb; ++b) { boff[b] = run; run += bsum[b]; }
    row_ptr[N] = run;
  }
}

__global__ __launch_bounds__(1024) void scan_add_k(int* __restrict__ row_ptr, int* __restrict__ cursor,
                                                   const int* __restrict__ boff, int N) {
  int i = blockIdx.x * 1024 + threadIdx.x;
  if (i < N) {
    int v = row_ptr[i] + boff[blockIdx.x];
    row_ptr[i] = v;
    cursor[i] = v;
  }
}

__global__ __launch_bounds__(256) void fill_k(const int* __restrict__ src, const int* __restrict__ tgt,
                                              int* __restrict__ cursor, int* __restrict__ srcs, int E) {
  int e = blockIdx.x * 256 + threadIdx.x;
  if (e < E) {
    int pos = atomicAdd(&cursor[tgt[e]], 1);
    srcs[pos] = src[e];
  }
}

// ---------------- conversions / weight packing ----------------
// x -> xb (bf16, GEMM A operand) and xh (fp16, gather payload)
__global__ __launch_bounds__(256) void conv_k(const float* __restrict__ x, unsigned short* __restrict__ xb,
                                              unsigned short* __restrict__ xh, int n4) {
  int i = blockIdx.x * 256 + threadIdx.x;
  if (i < n4) {
    float4 v = ((const float4*)x)[i];
    ((ushort2*)xb)[i * 2]     = make_ushort2(f2bf(v.x), f2bf(v.y));
    ((ushort2*)xb)[i * 2 + 1] = make_ushort2(f2bf(v.z), f2bf(v.w));
    ((ushort2*)xh)[i * 2]     = make_ushort2(f2h(v.x), f2h(v.y));
    ((ushort2*)xh)[i * 2 + 1] = make_ushort2(f2h(v.z), f2h(v.w));
  }
}

__device__ __forceinline__ void split_store(float v, unsigned short* hi, unsigned short* lo, int idx) {
  unsigned short h = f2bf(v);
  float hf = __uint_as_float(((unsigned)h) << 16);
  hi[idx] = h;
  lo[idx] = f2bf(v - hf);
}

__global__ __launch_bounds__(256) void pack_ksplit_k(const float* __restrict__ Wa, const float* __restrict__ Wb,
                                                     unsigned short* __restrict__ Whi, unsigned short* __restrict__ Wlo,
                                                     int Kh, int Ktot) {
  int t = blockIdx.x * 256 + threadIdx.x;
  if (t >= 256 * Ktot) return;
  int n = t / Ktot, k = t - n * Ktot;
  float v = (k < Kh) ? Wa[k * 256 + n] : Wb[(k - Kh) * 256 + n];
  split_store(v, Whi, Wlo, t);
}

__global__ __launch_bounds__(256) void pack_nsplit_k(const float* __restrict__ Wa, const float* __restrict__ Wb,
                                                     unsigned short* __restrict__ Whi, unsigned short* __restrict__ Wlo,
                                                     int K) {
  int t = blockIdx.x * 256 + threadIdx.x;
  if (t >= 256 * K) return;
  int n = t / K, k = t - n * K;
  float v = (n < 128) ? Wa[k * 128 + n] : Wb[k * 128 + (n - 128)];
  split_store(v, Whi, Wlo, t);
}

// Wc[128x8] = W_lin @ W_lin2; bc[8] = b_lin @ W_lin2 + b_lin2
__global__ __launch_bounds__(256) void comb_k(const float* __restrict__ Wlin, const float* __restrict__ blin,
                                              const float* __restrict__ Wlin2, const float* __restrict__ blin2,
                                              float* __restrict__ Wc, float* __restrict__ bc) {
  int t = blockIdx.x * 256 + threadIdx.x;
  if (t < 1024) {
    int i = t >> 3, j = t & 7;
    float acc = 0.f;
    for (int k = 0; k < 128; ++k) acc = fmaf(Wlin[i * 128 + k], Wlin2[k * 8 + j], acc);
    Wc[t] = acc;
  }
  if (t < 8) {
    float acc = blin2[t];
    for (int k = 0; k < 128; ++k) acc = fmaf(blin[k], Wlin2[k * 8 + t], acc);
    bc[t] = acc;
  }
}

// ---------------- aggregation ----------------
// wave per node, D=64 fp16 gather, 4-deep unroll; writes bf16 mean
__global__ __launch_bounds__(256) void agg_mean64_k(const unsigned short* __restrict__ xh, const int* __restrict__ rp,
                                                    const int* __restrict__ srcs, unsigned short* __restrict__ mb, int n) {
  int w = threadIdx.x >> 6, lane = threadIdx.x & 63;
  int node = blockIdx.x * 4 + w;
  if (node >= n) return;
  int s0 = rp[node], s1 = rp[node + 1];
  float sum = 0.f;
  int e = s0;
  for (; e + 3 < s1; e += 4) {
    int a = srcs[e], b = srcs[e + 1], c = srcs[e + 2], d = srcs[e + 3];
    float va = __half2float(__ushort_as_half(xh[(size_t)a * 64 + lane]));
    float vb = __half2float(__ushort_as_half(xh[(size_t)b * 64 + lane]));
    float vc = __half2float(__ushort_as_half(xh[(size_t)c * 64 + lane]));
    float vd = __half2float(__ushort_as_half(xh[(size_t)d * 64 + lane]));
    sum += (va + vb) + (vc + vd);
  }
  for (; e < s1; ++e)
    sum += __half2float(__ushort_as_half(xh[(size_t)srcs[e] * 64 + lane]));
  int deg = s1 - s0;
  float inv = 1.f / (float)(deg > 0 ? deg : 1);
  mb[(size_t)node * 64 + lane] = f2bf(sum * inv);
}

// wave per node, D=128 fp16 gather (ushort2/lane), 4-deep unroll.
// OUTMODE 1: hout = bf16 h (N x 128). OUTMODE 2: fused head -> out fp32 (N x 8).
template <int OUTMODE>
__global__ __launch_bounds__(256) void agg128_k(const unsigned short* __restrict__ yb,
                                                const unsigned short* __restrict__ zb,
                                                const float* __restrict__ bias,
                                                const int* __restrict__ rp, const int* __restrict__ srcs,
                                                void* __restrict__ hout,
                                                const float* __restrict__ Wc, const float* __restrict__ bc, int n) {
  int w = threadIdx.x >> 6, lane = threadIdx.x & 63;
  int node = blockIdx.x * 4 + w;
  if (node >= n) return;
  int s0 = rp[node], s1 = rp[node + 1];
  int d = lane * 2;
  float sx = 0.f, sy = 0.f;
  int e = s0;
  for (; e + 3 < s1; e += 4) {
    int a = srcs[e], b = srcs[e + 1], c = srcs[e + 2], dd = srcs[e + 3];
    float2 v0 = ld_h2(yb, (size_t)a * 128 + d);
    float2 v1 = ld_h2(yb, (size_t)b * 128 + d);
    float2 v2 = ld_h2(yb, (size_t)c * 128 + d);
    float2 v3 = ld_h2(yb, (size_t)dd * 128 + d);
    sx += (v0.x + v1.x) + (v2.x + v3.x);
    sy += (v0.y + v1.y) + (v2.y + v3.y);
  }
  for (; e < s1; ++e) {
    float2 v = ld_h2(yb, (size_t)srcs[e] * 128 + d);
    sx += v.x; sy += v.y;
  }
  int deg = s1 - s0;
  float inv = 1.f / (float)(deg > 0 ? deg : 1);
  float2 z = ld_h2(zb, (size_t)node * 128 + d);
  float2 b2 = *(const float2*)&bias[d];
  float ox = fmaxf(fmaf(sx, inv, z.x + b2.x), 0.f);
  float oy = fmaxf(fmaf(sy, inv, z.y + b2.y), 0.f);

  if (OUTMODE == 1) {
    ((ushort2*)hout)[((size_t)node * 128 + d) / 2] = make_ushort2(f2bf(ox), f2bf(oy));
  } else {
    // fused head: out[node][j] = sum_d o_d * Wc[d][j] + bc[j]
    const float4* wr = (const float4*)&Wc[d * 8];   // rows d, d+1 (16 floats), L1-hot
    float4 wa0 = wr[0], wa1 = wr[1], wb0 = wr[2], wb1 = wr[3];
    float a8[8];
    a8[0] = ox * wa0.x + oy * wb0.x;
    a8[1] = ox * wa0.y + oy * wb0.y;
    a8[2] = ox * wa0.z + oy * wb0.z;
    a8[3] = ox * wa0.w + oy * wb0.w;
    a8[4] = ox * wa1.x + oy * wb1.x;
    a8[5] = ox * wa1.y + oy * wb1.y;
    a8[6] = ox * wa1.z + oy * wb1.z;
    a8[7] = ox * wa1.w + oy * wb1.w;
#pragma unroll
    for (int off = 32; off >= 1; off >>= 1) {
#pragma unroll
      for (int j = 0; j < 8; ++j) a8[j] += __shfl_xor(a8[j], off);
    }
    if (lane == 0) {
      float* o = (float*)hout + (size_t)node * 8;
      float4 o0 = make_float4(a8[0] + bc[0], a8[1] + bc[1], a8[2] + bc[2], a8[3] + bc[3]);
      float4 o1 = make_float4(a8[4] + bc[4], a8[5] + bc[5], a8[6] + bc[6], a8[7] + bc[7]);
      *(float4*)o = o0;
      *(float4*)(o + 4) = o1;
    }
  }
}

// ---------------- MFMA GEMM ----------------
// Block tile 128x128, 4 waves (2x2), each wave 64x64 via 4x4 frags of 16x16x32 bf16 MFMA.
// MODE 0: fp16 out, split into Y (cols 0..127) / Z (cols 128..255) dense buffers, ld 128.
// MODE 1: bias+relu -> bf16 out Ob (ldc 256).
template <int MODE>
__global__ __launch_bounds__(256) void gemm_mfma_k(Segs segs, const float* __restrict__ bias,
                                                   unsigned short* __restrict__ Y, unsigned short* __restrict__ Z,
                                                   unsigned short* __restrict__ Ob, int ldc) {
  __shared__ unsigned short Asl[128 * 32];
  __shared__ unsigned short Wsl[128 * 32];
  int tid = threadIdx.x;
  int lane = tid & 63, wave = tid >> 6;
  int wm = wave & 1, wn = wave >> 1;
  int rowBase = blockIdx.x * 128, colBase = blockIdx.y * 128;
  f32x4 acc[4][4] = {};

  int c0 = tid, c1 = tid + 256;
  int r0 = c0 >> 2, q0 = c0 & 3;
  int r1 = c1 >> 2, q1 = c1 & 3;
  int ml = lane & 15, qq = lane >> 4;

  for (int si = 0; si < segs.n; ++si) {
    const unsigned short* Aseg = segs.s[si].A;
    const unsigned short* Wseg = segs.s[si].W;
    int lda = segs.s[si].lda, ldw = segs.s[si].ldw, K = segs.s[si].K;
    for (int k0 = 0; k0 < K; k0 += 32) {
      uint4 av0 = *(const uint4*)&Aseg[(size_t)(rowBase + r0) * lda + k0 + q0 * 8];
      uint4 av1 = *(const uint4*)&Aseg[(size_t)(rowBase + r1) * lda + k0 + q1 * 8];
      uint4 wv0 = *(const uint4*)&Wseg[(size_t)(colBase + r0) * ldw + k0 + q0 * 8];
      uint4 wv1 = *(const uint4*)&Wseg[(size_t)(colBase + r1) * ldw + k0 + q1 * 8];
      __syncthreads();
      *(uint4*)&Asl[c0 * 8] = av0;
      *(uint4*)&Asl[c1 * 8] = av1;
      *(uint4*)&Wsl[c0 * 8] = wv0;
      *(uint4*)&Wsl[c1 * 8] = wv1;
      __syncthreads();
      bf16x8 af[4], bw[4];
#pragma unroll
      for (int i = 0; i < 4; ++i) {
        af[i] = *(bf16x8*)&Asl[(wm * 64 + i * 16 + ml) * 32 + qq * 8];
        bw[i] = *(bf16x8*)&Wsl[(wn * 64 + i * 16 + ml) * 32 + qq * 8];
      }
#pragma unroll
      for (int mf = 0; mf < 4; ++mf)
#pragma unroll
        for (int nf = 0; nf < 4; ++nf)
          acc[mf][nf] = __builtin_amdgcn_mfma_f32_16x16x32_bf16(af[mf], bw[nf], acc[mf][nf], 0, 0, 0);
    }
  }

  if (MODE == 0) {
    unsigned short* dst = (colBase == 0) ? Y : Z;
#pragma unroll
    for (int mf = 0; mf < 4; ++mf) {
      int row = rowBase + wm * 64 + mf * 16 + qq * 4;
#pragma unroll
      for (int nf = 0; nf < 4; ++nf) {
        int col = wn * 64 + nf * 16 + ml;   // 0..127 within the half
#pragma unroll
        for (int r = 0; r < 4; ++r)
          dst[(size_t)(row + r) * 128 + col] = f2h(acc[mf][nf][r]);
      }
    }
  } else {
    float bc4[4];
#pragma unroll
    for (int nf = 0; nf < 4; ++nf) bc4[nf] = bias[colBase + wn * 64 + nf * 16 + ml];
#pragma unroll
    for (int mf = 0; mf < 4; ++mf) {
      int row = rowBase + wm * 64 + mf * 16 + qq * 4;
#pragma unroll
      for (int nf = 0; nf < 4; ++nf) {
        int col = colBase + wn * 64 + nf * 16 + ml;
#pragma unroll
        for (int r = 0; r < 4; ++r) {
          float o = fmaxf(acc[mf][nf][r] + bc4[nf], 0.f);
          Ob[(size_t)(row + r) * ldc + col] = f2bf(o);
        }
      }
    }
  }
}

// ---------------- host ----------------
extern "C" void kernel_launch(void* const* d_in, const int* in_sizes, int n_in,
                              void* d_out, int out_size, void* d_ws, size_t ws_size,
                              hipStream_t stream) {
  const float* x      = (const float*)d_in[0];
  const int*   ei     = (const int*)d_in[1];
  const float* Wf_l   = (const float*)d_in[2];
  const float* bf     = (const float*)d_in[3];
  const float* Wf_r   = (const float*)d_in[4];
  const float* W0_l   = (const float*)d_in[5];
  const float* b0     = (const float*)d_in[6];
  const float* W0_r   = (const float*)d_in[7];
  const float* W1_l   = (const float*)d_in[8];
  const float* b1     = (const float*)d_in[9];
  const float* W1_r   = (const float*)d_in[10];
  const float* W_lin  = (const float*)d_in[11];
  const float* b_lin  = (const float*)d_in[12];
  const float* W_lin2 = (const float*)d_in[13];
  const float* b_lin2 = (const float*)d_in[14];
  float* out = (float*)d_out;

  const int N = in_sizes[0] / 64;           // 50000
  const int E = in_sizes[1] / 2;            // 800000
  const int Npad = ((N + 127) / 128) * 128; // 50048
  const int nblkM = Npad / 128;
  const int* e_src = ei;
  const int* e_tgt = ei + E;

  size_t off = 0;
  char* base = (char*)d_ws;
  auto carve = [&](size_t bytes) -> void* {
    void* p = base + off;
    off += (bytes + 255) & ~(size_t)255;
    return p;
  };
  int*   row_ptr = (int*)carve((size_t)(N + 1) * 4);
  int*   cursor  = (int*)carve((size_t)N * 4);
  int*   bsum    = (int*)carve(64 * 4);
  int*   boff    = (int*)carve(64 * 4);
  int*   srcs    = (int*)carve((size_t)E * 4);
  unsigned short* xb    = (unsigned short*)carve((size_t)Npad * 64 * 2);
  unsigned short* xh    = (unsigned short*)carve((size_t)Npad * 64 * 2);
  unsigned short* mb    = (unsigned short*)carve((size_t)Npad * 64 * 2);
  unsigned short* h1b   = (unsigned short*)carve((size_t)Npad * 256 * 2);
  unsigned short* h2b   = (unsigned short*)carve((size_t)Npad * 128 * 2);
  unsigned short* yb    = (unsigned short*)carve((size_t)Npad * 128 * 2);
  unsigned short* zb    = (unsigned short*)carve((size_t)Npad * 128 * 2);
  unsigned short* Wt1hi = (unsigned short*)carve(256 * 128 * 2);
  unsigned short* Wt1lo = (unsigned short*)carve(256 * 128 * 2);
  unsigned short* Wt2hi = (unsigned short*)carve(256 * 256 * 2);
  unsigned short* Wt2lo = (unsigned short*)carve(256 * 256 * 2);
  unsigned short* Wt3hi = (unsigned short*)carve(256 * 128 * 2);
  unsigned short* Wt3lo = (unsigned short*)carve(256 * 128 * 2);
  float* Wcomb = (float*)carve(1024 * 4);
  float* bcomb = (float*)carve(8 * 4);
  (void)ws_size; (void)n_in; (void)out_size;

  const int nbE   = (E + 255) / 256;
  const int nbScn = (N + 1023) / 1024;

  // CSR build
  hipMemsetAsync(cursor, 0, (size_t)N * 4, stream);
  count_k<<<nbE, 256, 0, stream>>>(e_tgt, cursor, E);
  scan_block_k<<<nbScn, 1024, 0, stream>>>(cursor, row_ptr, bsum, N);
  scan_bsum_k<<<1, 64, 0, stream>>>(bsum, boff, row_ptr, nbScn, N);
  scan_add_k<<<nbScn, 1024, 0, stream>>>(row_ptr, cursor, boff, N);
  fill_k<<<nbE, 256, 0, stream>>>(e_src, e_tgt, cursor, srcs, E);

  // conversions + packing + head fold
  conv_k<<<(N * 16 + 255) / 256, 256, 0, stream>>>(x, xb, xh, N * 16);
  pack_ksplit_k<<<(256 * 128 + 255) / 256, 256, 0, stream>>>(Wf_l, Wf_r, Wt1hi, Wt1lo, 64, 128);
  pack_nsplit_k<<<(256 * 256 + 255) / 256, 256, 0, stream>>>(W0_l, W0_r, Wt2hi, Wt2lo, 256);
  pack_nsplit_k<<<(256 * 128 + 255) / 256, 256, 0, stream>>>(W1_l, W1_r, Wt3hi, Wt3lo, 128);
  comb_k<<<4, 256, 0, stream>>>(W_lin, b_lin, W_lin2, b_lin2, Wcomb, bcomb);

  const int nbAgg = (N + 3) / 4;
  const dim3 gemmGrid(nblkM, 2);

  // Layer 1
  agg_mean64_k<<<nbAgg, 256, 0, stream>>>(xh, row_ptr, srcs, mb, N);
  {
    Segs s;
    s.n = 4;
    s.s[0] = {mb, Wt1hi,      64, 128, 64};
    s.s[1] = {xb, Wt1hi + 64, 64, 128, 64};
    s.s[2] = {mb, Wt1lo,      64, 128, 64};
    s.s[3] = {xb, Wt1lo + 64, 64, 128, 64};
    gemm_mfma_k<1><<<gemmGrid, 256, 0, stream>>>(s, bf, nullptr, nullptr, h1b, 256);
  }

  // Layer 2
  {
    Segs s;
    s.n = 2;
    s.s[0] = {h1b, Wt2hi, 256, 256, 256};
    s.s[1] = {h1b, Wt2lo, 256, 256, 256};
    s.s[2] = {nullptr, nullptr, 0, 0, 0};
    s.s[3] = {nullptr, nullptr, 0, 0, 0};
    gemm_mfma_k<0><<<gemmGrid, 256, 0, stream>>>(s, nullptr, yb, zb, nullptr, 256);
  }
  agg128_k<1><<<nbAgg, 256, 0, stream>>>(yb, zb, b0, row_ptr, srcs, h2b, nullptr, nullptr, N);

  // Layer 3 + fused head
  {
    Segs s;
    s.n = 2;
    s.s[0] = {h2b, Wt3hi, 128, 128, 128};
    s.s[1] = {h2b, Wt3lo, 128, 128, 128};
    s.s[2] = {nullptr, nullptr, 0, 0, 0};
    s.s[3] = {nullptr, nullptr, 0, 0, 0};
    gemm_mfma_k<0><<<gemmGrid, 256, 0, stream>>>(s, nullptr, yb, zb, nullptr, 256);
  }
  agg128_k<2><<<nbAgg, 256, 0, stream>>>(yb, zb, b1, row_ptr, srcs, out, Wcomb, bcomb, N);
}